// Round 9
// baseline (68.127 us; speedup 1.0000x reference)
//
#include <hip/hip_runtime.h>
#include <hip/hip_bf16.h>

// Problem constants: B=8, C=64, C8=8, H=128, W=128
#define BDIM 8
#define CDIM 64
#define C8DIM 8
#define HDIM 128
#define WDIM 128
#define HW (HDIM * WDIM)   // 16384

typedef short bf16x8 __attribute__((ext_vector_type(8)));
typedef float f32x4 __attribute__((ext_vector_type(4)));

// ---------------- bf16 helpers ----------------
__device__ inline unsigned pk_bf16(float a, float b) {
    unsigned ua = (unsigned)__bfloat16_as_ushort(__float2bfloat16(a));
    unsigned ub = (unsigned)__bfloat16_as_ushort(__float2bfloat16(b));
    return ua | (ub << 16);
}
__device__ inline void cvt2(unsigned u, float& lo, float& hi) {
    lo = __uint_as_float(u << 16);
    hi = __uint_as_float(u & 0xffff0000u);
}

// ---------------------------------------------------------------------------
// Kernel 1: fused QKV projection as MFMA GEMM (round-5 structure: 1024 blocks,
// direct epilogue stores, no post-GEMM barriers, no xy side-output).
//   D[o][p] = sum_c Wall[o][c] * X[c][p],  o in [0,80), c in [0,128)
// One block per (b, 128-position tile). 4 waves; wave covers 32 positions
// (2 n-tiles), all 5 m-tiles, K=128 as 2 pairs of (x-ch 32, y-ch 32).
// Weights: LDS bf16 [o][c] XOR-swizzled; X/Y: direct per-lane global loads.
// C/D layout: col = lane&15 (p), row = (lane>>4)*4 + reg (o) [HW-verified].
// ---------------------------------------------------------------------------
__global__ __launch_bounds__(256) void qkv_kernel(
    const float* __restrict__ x, const float* __restrict__ y,
    const float* __restrict__ Wq, const float* __restrict__ bq,
    const float* __restrict__ Wk, const float* __restrict__ bk,
    const float* __restrict__ Wv, const float* __restrict__ bv,
    uint4* __restrict__ q_pm, uint4* __restrict__ k_pm, uint4* __restrict__ v_pm)
{
    __shared__ ushort sW[80 * 128];   // [o][c] bf16, XOR-swizzled
    __shared__ float  sb[80];

    const int t = threadIdx.x;

    // ---- stage weights: 80x64 uint (=2 bf16) elements ----
    for (int i = t; i < 80 * 64; i += 256) {
        int o  = i >> 6;
        int cp = i & 63;
        int c  = cp * 2;
        float w0, w1;
        if (o < 8) {
            if (c < 64) { w0 = Wq[o * 64 + c]; w1 = Wq[o * 64 + c + 1]; }
            else        { w0 = 0.f; w1 = 0.f; }
        } else if (o < 16) {
            if (c >= 64) { w0 = Wk[(o - 8) * 64 + c - 64]; w1 = Wk[(o - 8) * 64 + c - 63]; }
            else         { w0 = 0.f; w1 = 0.f; }
        } else {
            w0 = Wv[(o - 16) * 128 + c];
            w1 = Wv[(o - 16) * 128 + c + 1];
        }
        ((unsigned*)sW)[o * 64 + (cp ^ ((o & 7) << 2))] = pk_bf16(w0, w1);
    }
    if (t < 80) {
        sb[t] = (t < 8) ? bq[t] : (t < 16) ? bk[t - 8] : bv[t - 16];
    }
    __syncthreads();

    const int blk = blockIdx.x;
    const int b   = blk & 7;
    const int p0  = (blk >> 3) << 7;    // position tile base

    const int wv = t >> 6, ln = t & 63, lg = ln >> 4, li = ln & 15;
    const int pcol0 = p0 + wv * 32 + li;   // this lane's n=0 position

    const float* xb = x + (size_t)b * CDIM * HW;
    const float* yb = y + (size_t)b * CDIM * HW;

    f32x4 acc[5][2];
    #pragma unroll
    for (int mt = 0; mt < 5; mt++)
        #pragma unroll
        for (int n = 0; n < 2; n++) acc[mt][n] = (f32x4){0.f, 0.f, 0.f, 0.f};

    #pragma unroll
    for (int pair = 0; pair < 2; pair++) {
        const int chb = pair * 32 + lg * 8;          // x/y channel base
        const float* xp = xb + (size_t)chb * HW;
        const float* yp = yb + (size_t)chb * HW;
        bf16x8 bx[2], by[2];
        #pragma unroll
        for (int n = 0; n < 2; n++) {
            const size_t poff = (size_t)(pcol0 + n * 16);
            float fx[8], fy[8];
            #pragma unroll
            for (int e = 0; e < 8; e++) {
                fx[e] = xp[(size_t)e * HW + poff];
                fy[e] = yp[(size_t)e * HW + poff];
            }
            uint4 ux, uy;
            ux.x = pk_bf16(fx[0], fx[1]); ux.y = pk_bf16(fx[2], fx[3]);
            ux.z = pk_bf16(fx[4], fx[5]); ux.w = pk_bf16(fx[6], fx[7]);
            uy.x = pk_bf16(fy[0], fy[1]); uy.y = pk_bf16(fy[2], fy[3]);
            uy.z = pk_bf16(fy[4], fy[5]); uy.w = pk_bf16(fy[6], fy[7]);
            bx[n] = *(bf16x8*)&ux;
            by[n] = *(bf16x8*)&uy;
        }
        #pragma unroll
        for (int mt = 0; mt < 5; mt++) {
            const int row = mt * 16 + li;
            const int sw  = ((li & 7) << 3);
            bf16x8 ax = *(const bf16x8*)&sW[row * 128 + ((pair * 32 + lg * 8) ^ sw)];
            bf16x8 ay = *(const bf16x8*)&sW[row * 128 + (((2 + pair) * 32 + lg * 8) ^ sw)];
            #pragma unroll
            for (int n = 0; n < 2; n++) {
                acc[mt][n] = __builtin_amdgcn_mfma_f32_16x16x32_bf16(ax, bx[n], acc[mt][n], 0, 0, 0);
                acc[mt][n] = __builtin_amdgcn_mfma_f32_16x16x32_bf16(ay, by[n], acc[mt][n], 0, 0, 0);
            }
        }
    }

    // ---- epilogue: +bias, pack 4 contiguous o, direct store (pos-major) ----
    #pragma unroll
    for (int mt = 0; mt < 5; mt++) {
        const int ob = mt * 16 + lg * 4;   // o base (multiple of 4)
        const float b0 = sb[ob + 0], b1 = sb[ob + 1], b2 = sb[ob + 2], b3 = sb[ob + 3];
        #pragma unroll
        for (int n = 0; n < 2; n++) {
            const size_t gp = (size_t)b * HW + (size_t)(pcol0 + n * 16);
            uint2 w;
            w.x = pk_bf16(acc[mt][n][0] + b0, acc[mt][n][1] + b1);
            w.y = pk_bf16(acc[mt][n][2] + b2, acc[mt][n][3] + b3);
            ushort* dst;
            if (ob < 8)       dst = (ushort*)q_pm + gp * 8 + ob;
            else if (ob < 16) dst = (ushort*)k_pm + gp * 8 + (ob - 8);
            else              dst = (ushort*)v_pm + gp * 64 + (ob - 16);
            *(uint2*)dst = w;
        }
    }
}

// ---------------------------------------------------------------------------
// Kernel 2 (column branch): one block per (b, c).  MFMA tile-GEMMs:
//   QK^T (swapped): D[j][i] = sum_ch K[j][ch] * Q[ch][i]
//   per-row (i) softmax with diag mask, unnormalized
//   PV: D2[ch][i] = sum_j V[ch][j] * P[j][i]
// H_t[b][row=i][col=cc][ch] stored via P_lds-reuse transpose (full-line writes).
// ---------------------------------------------------------------------------
__global__ __launch_bounds__(256, 2) void colattn_kernel(
    const uint4* __restrict__ q_pm, const uint4* __restrict__ k_pm,
    const uint4* __restrict__ v_pm,
    ushort* __restrict__ H_t, float* __restrict__ mH_g, float* __restrict__ sH_g)
{
    __shared__ ushort Q_lds[128 * 8];     // [i][ch]
    __shared__ ushort K_lds[128 * 8];     // [j][ch]
    __shared__ ushort V_lds[64 * 136];    // [ch][j], pad 8
    __shared__ ushort P_lds[128 * 136];   // [i][j], pad 8; reused for H store

    const int blk = blockIdx.x;
    const int b  = blk & 7;
    const int cc = blk >> 3;
    const int t  = threadIdx.x;

    if (t < 128) {
        *(uint4*)&Q_lds[t * 8] = q_pm[(size_t)b * HW + (size_t)t * 128 + cc];
    } else {
        int j = t - 128;
        *(uint4*)&K_lds[j * 8] = k_pm[(size_t)b * HW + (size_t)j * 128 + cc];
    }
    {
        int j = t & 127, h = t >> 7;
        const uint4* vp = v_pm + ((size_t)b * HW + (size_t)j * 128 + cc) * 8 + 4 * h;
        #pragma unroll
        for (int qd = 0; qd < 4; qd++) {
            uint4 vu = vp[qd];
            int ch0 = 32 * h + 8 * qd;
            V_lds[(ch0 + 0) * 136 + j] = (ushort)(vu.x & 0xffff);
            V_lds[(ch0 + 1) * 136 + j] = (ushort)(vu.x >> 16);
            V_lds[(ch0 + 2) * 136 + j] = (ushort)(vu.y & 0xffff);
            V_lds[(ch0 + 3) * 136 + j] = (ushort)(vu.y >> 16);
            V_lds[(ch0 + 4) * 136 + j] = (ushort)(vu.z & 0xffff);
            V_lds[(ch0 + 5) * 136 + j] = (ushort)(vu.z >> 16);
            V_lds[(ch0 + 6) * 136 + j] = (ushort)(vu.w & 0xffff);
            V_lds[(ch0 + 7) * 136 + j] = (ushort)(vu.w >> 16);
        }
    }
    __syncthreads();

    const int wv = t >> 6, ln = t & 63, lg = ln >> 4, li = ln & 15;
    const bf16x8 zf = {0, 0, 0, 0, 0, 0, 0, 0};

    // ---- QK^T ----
    bf16x8 afr[8], bfr[2];
    #pragma unroll
    for (int jt = 0; jt < 8; jt++)
        afr[jt] = (lg == 0) ? *(const bf16x8*)&K_lds[(jt * 16 + li) * 8] : zf;
    #pragma unroll
    for (int it2 = 0; it2 < 2; it2++)
        bfr[it2] = (lg == 0) ? *(const bf16x8*)&Q_lds[((2 * wv + it2) * 16 + li) * 8] : zf;

    f32x4 dfr[2][8];
    #pragma unroll
    for (int a = 0; a < 2; a++)
        #pragma unroll
        for (int jt = 0; jt < 8; jt++) dfr[a][jt] = (f32x4){0.f, 0.f, 0.f, 0.f};

    #pragma unroll
    for (int it2 = 0; it2 < 2; it2++)
        #pragma unroll
        for (int jt = 0; jt < 8; jt++)
            dfr[it2][jt] = __builtin_amdgcn_mfma_f32_16x16x32_bf16(
                afr[jt], bfr[it2], dfr[it2][jt], 0, 0, 0);

    // ---- softmax (unnormalized, diag masked) ----
    #pragma unroll
    for (int it2 = 0; it2 < 2; it2++) {
        const int i = (2 * wv + it2) * 16 + li;
        float m = -1e30f;
        #pragma unroll
        for (int jt = 0; jt < 8; jt++)
            #pragma unroll
            for (int rr = 0; rr < 4; rr++) {
                int j = jt * 16 + lg * 4 + rr;
                float e = dfr[it2][jt][rr];
                if (j == i) e = -1e30f;
                dfr[it2][jt][rr] = e;
                m = fmaxf(m, e);
            }
        m = fmaxf(m, __shfl_xor(m, 16));
        m = fmaxf(m, __shfl_xor(m, 32));
        float s = 0.f;
        #pragma unroll
        for (int jt = 0; jt < 8; jt++)
            #pragma unroll
            for (int rr = 0; rr < 4; rr++) {
                float p = __expf(dfr[it2][jt][rr] - m);
                dfr[it2][jt][rr] = p;
                s += p;
            }
        s += __shfl_xor(s, 16);
        s += __shfl_xor(s, 32);
        #pragma unroll
        for (int jt = 0; jt < 8; jt++) {
            uint2 w;
            w.x = pk_bf16(dfr[it2][jt][0], dfr[it2][jt][1]);
            w.y = pk_bf16(dfr[it2][jt][2], dfr[it2][jt][3]);
            *(uint2*)&P_lds[(size_t)i * 136 + jt * 16 + lg * 4] = w;
        }
        if (lg == 0) {
            mH_g[((size_t)b * 128 + cc) * 128 + i] = m;
            sH_g[((size_t)b * 128 + cc) * 128 + i] = s;
        }
    }
    __syncthreads();

    // ---- PV ----
    f32x4 ofr[8];
    #pragma unroll
    for (int itl = 0; itl < 8; itl++) ofr[itl] = (f32x4){0.f, 0.f, 0.f, 0.f};

    #pragma unroll
    for (int ks = 0; ks < 4; ks++) {
        const int jb = ks * 32 + lg * 8;
        bf16x8 av = *(const bf16x8*)&V_lds[(wv * 16 + li) * 136 + jb];
        #pragma unroll
        for (int itl = 0; itl < 8; itl++) {
            bf16x8 bp = *(const bf16x8*)&P_lds[(itl * 16 + li) * 136 + jb];
            ofr[itl] = __builtin_amdgcn_mfma_f32_16x16x32_bf16(av, bp, ofr[itl], 0, 0, 0);
        }
    }
    __syncthreads();   // P_lds dead; reuse as H transpose buffer [128][72]

    #pragma unroll
    for (int itl = 0; itl < 8; itl++) {
        const int i = itl * 16 + li;
        uint2 w;
        w.x = pk_bf16(ofr[itl][0], ofr[itl][1]);
        w.y = pk_bf16(ofr[itl][2], ofr[itl][3]);
        *(uint2*)&P_lds[i * 72 + wv * 16 + lg * 4] = w;
    }
    __syncthreads();

    #pragma unroll
    for (int i2 = 0; i2 < 4; i2++) {
        const int f = t + i2 * 256;          // 128 i x 8 chunks
        const int i = f >> 3, cb = (f & 7) * 8;
        *(uint4*)&H_t[(((size_t)b * 128 + i) * 128 + cc) * 64 + cb] =
            *(const uint4*)&P_lds[i * 72 + cb];
    }
}

// ---------------------------------------------------------------------------
// Kernel 3 (row branch + merge): one block per (b, r).  Same GEMM structure
// (no diag mask); epilogue merges with the column branch (mH/sH/H_t) and adds
// the residual:  out = (H*wH + W*wW) * gamma/(sH*wH + sW*wW) + x + y.
// x,y read as fp32 at the same index as the out write (coalesced, L3-hot).
// ---------------------------------------------------------------------------
__global__ __launch_bounds__(256, 2) void rowattn_kernel(
    const uint4* __restrict__ q_pm, const uint4* __restrict__ k_pm,
    const uint4* __restrict__ v_pm,
    const ushort* __restrict__ H_t, const float* __restrict__ mH_g,
    const float* __restrict__ sH_g,
    const float* __restrict__ x, const float* __restrict__ y,
    const float* __restrict__ gptr, float* __restrict__ out)
{
    __shared__ ushort Q_lds[128 * 8];     // [i][ch]  (i = column index)
    __shared__ ushort K_lds[128 * 8];     // [j][ch]
    __shared__ ushort V_lds[64 * 136];    // [ch][j]
    __shared__ ushort P_lds[128 * 136];   // [i][j]
    __shared__ float mW_s[128], sW_s[128];

    const int blk = blockIdx.x;
    const int b = blk & 7;
    const int r = blk >> 3;
    const int t = threadIdx.x;

    if (t < 128) {
        *(uint4*)&Q_lds[t * 8] = q_pm[(size_t)b * HW + (size_t)r * 128 + t];
    } else {
        int j = t - 128;
        *(uint4*)&K_lds[j * 8] = k_pm[(size_t)b * HW + (size_t)r * 128 + j];
    }
    {
        int j = t & 127, h = t >> 7;
        const uint4* vp = v_pm + ((size_t)b * HW + (size_t)r * 128 + j) * 8 + 4 * h;
        #pragma unroll
        for (int qd = 0; qd < 4; qd++) {
            uint4 vu = vp[qd];
            int ch0 = 32 * h + 8 * qd;
            V_lds[(ch0 + 0) * 136 + j] = (ushort)(vu.x & 0xffff);
            V_lds[(ch0 + 1) * 136 + j] = (ushort)(vu.x >> 16);
            V_lds[(ch0 + 2) * 136 + j] = (ushort)(vu.y & 0xffff);
            V_lds[(ch0 + 3) * 136 + j] = (ushort)(vu.y >> 16);
            V_lds[(ch0 + 4) * 136 + j] = (ushort)(vu.z & 0xffff);
            V_lds[(ch0 + 5) * 136 + j] = (ushort)(vu.z >> 16);
            V_lds[(ch0 + 6) * 136 + j] = (ushort)(vu.w & 0xffff);
            V_lds[(ch0 + 7) * 136 + j] = (ushort)(vu.w >> 16);
        }
    }
    __syncthreads();

    const int wv = t >> 6, ln = t & 63, lg = ln >> 4, li = ln & 15;
    const bf16x8 zf = {0, 0, 0, 0, 0, 0, 0, 0};

    bf16x8 afr[8], bfr[2];
    #pragma unroll
    for (int jt = 0; jt < 8; jt++)
        afr[jt] = (lg == 0) ? *(const bf16x8*)&K_lds[(jt * 16 + li) * 8] : zf;
    #pragma unroll
    for (int it2 = 0; it2 < 2; it2++)
        bfr[it2] = (lg == 0) ? *(const bf16x8*)&Q_lds[((2 * wv + it2) * 16 + li) * 8] : zf;

    f32x4 dfr[2][8];
    #pragma unroll
    for (int a = 0; a < 2; a++)
        #pragma unroll
        for (int jt = 0; jt < 8; jt++) dfr[a][jt] = (f32x4){0.f, 0.f, 0.f, 0.f};

    #pragma unroll
    for (int it2 = 0; it2 < 2; it2++)
        #pragma unroll
        for (int jt = 0; jt < 8; jt++)
            dfr[it2][jt] = __builtin_amdgcn_mfma_f32_16x16x32_bf16(
                afr[jt], bfr[it2], dfr[it2][jt], 0, 0, 0);

    #pragma unroll
    for (int it2 = 0; it2 < 2; it2++) {
        const int i = (2 * wv + it2) * 16 + li;
        float m = -1e30f;
        #pragma unroll
        for (int jt = 0; jt < 8; jt++)
            #pragma unroll
            for (int rr = 0; rr < 4; rr++)
                m = fmaxf(m, dfr[it2][jt][rr]);
        m = fmaxf(m, __shfl_xor(m, 16));
        m = fmaxf(m, __shfl_xor(m, 32));
        float s = 0.f;
        #pragma unroll
        for (int jt = 0; jt < 8; jt++)
            #pragma unroll
            for (int rr = 0; rr < 4; rr++) {
                float p = __expf(dfr[it2][jt][rr] - m);
                dfr[it2][jt][rr] = p;
                s += p;
            }
        s += __shfl_xor(s, 16);
        s += __shfl_xor(s, 32);
        #pragma unroll
        for (int jt = 0; jt < 8; jt++) {
            uint2 w;
            w.x = pk_bf16(dfr[it2][jt][0], dfr[it2][jt][1]);
            w.y = pk_bf16(dfr[it2][jt][2], dfr[it2][jt][3]);
            *(uint2*)&P_lds[(size_t)i * 136 + jt * 16 + lg * 4] = w;
        }
        if (lg == 0) {
            mW_s[i] = m;
            sW_s[i] = s;
        }
    }
    __syncthreads();

    f32x4 ofr[8];
    #pragma unroll
    for (int itl = 0; itl < 8; itl++) ofr[itl] = (f32x4){0.f, 0.f, 0.f, 0.f};

    #pragma unroll
    for (int ks = 0; ks < 4; ks++) {
        const int jb = ks * 32 + lg * 8;
        bf16x8 av = *(const bf16x8*)&V_lds[(wv * 16 + li) * 136 + jb];
        #pragma unroll
        for (int itl = 0; itl < 8; itl++) {
            bf16x8 bp = *(const bf16x8*)&P_lds[(itl * 16 + li) * 136 + jb];
            ofr[itl] = __builtin_amdgcn_mfma_f32_16x16x32_bf16(av, bp, ofr[itl], 0, 0, 0);
        }
    }

    const float gamma = gptr[0];
    #pragma unroll
    for (int itl = 0; itl < 8; itl++) {
        const int i = itl * 16 + li;     // column index of this position
        float mWv = mW_s[i], sWv = sW_s[i];
        float mHv = mH_g[((size_t)b * 128 + i) * 128 + r];
        float sHv = sH_g[((size_t)b * 128 + i) * 128 + r];
        float m  = fmaxf(mHv, mWv);
        float wH = __expf(mHv - m);
        float wW = __expf(mWv - m);
        float invg = gamma / (sHv * wH + sWv * wW);

        // coalesced-footprint H read: [b][r][i][ch], 8B per lane per itl
        uint2 hw = *(const uint2*)&H_t[(((size_t)b * 128 + r) * 128 + i) * 64 + wv * 16 + lg * 4];
        float h[4];
        cvt2(hw.x, h[0], h[1]);
        cvt2(hw.y, h[2], h[3]);

        #pragma unroll
        for (int rr = 0; rr < 4; rr++) {
            const int ch = wv * 16 + lg * 4 + rr;
            size_t o = (((size_t)b * 64 + ch) * 128 + r) * 128 + i;
            out[o] = (h[rr] * wH + ofr[itl][rr] * wW) * invg + x[o] + y[o];
        }
    }
}

// ---------------------------------------------------------------------------
extern "C" void kernel_launch(void* const* d_in, const int* in_sizes, int n_in,
                              void* d_out, int out_size, void* d_ws, size_t ws_size,
                              hipStream_t stream)
{
    const float* x     = (const float*)d_in[0];
    const float* y     = (const float*)d_in[1];
    const float* Wq    = (const float*)d_in[2];
    const float* bq    = (const float*)d_in[3];
    const float* Wk    = (const float*)d_in[4];
    const float* bk    = (const float*)d_in[5];
    const float* Wv    = (const float*)d_in[6];
    const float* bv    = (const float*)d_in[7];
    const float* gamma = (const float*)d_in[8];
    float* out = (float*)d_out;

    // Workspace: q 2MB | k 2MB | v 16MB | H_t 16MB | mH .5MB | sH .5MB
    uint4*  q_pm = (uint4*)d_ws;                        // 131072 uint4
    uint4*  k_pm = q_pm + (size_t)BDIM * HW;            // 131072 uint4
    uint4*  v_pm = k_pm + (size_t)BDIM * HW;            // 1048576 uint4
    ushort* H_t  = (ushort*)(v_pm + (size_t)BDIM * HW * 8);      // 8388608 us
    float*  mH   = (float*)(H_t + (size_t)BDIM * HW * 64);
    float*  sH   = mH + (size_t)BDIM * HW;

    qkv_kernel<<<dim3(BDIM * HW / 128), dim3(256), 0, stream>>>(
        x, y, Wq, bq, Wk, bk, Wv, bv, q_pm, k_pm, v_pm);

    colattn_kernel<<<dim3(BDIM * WDIM), dim3(256), 0, stream>>>(
        q_pm, k_pm, v_pm, H_t, mH, sH);

    rowattn_kernel<<<dim3(BDIM * HDIM), dim3(256), 0, stream>>>(
        q_pm, k_pm, v_pm, H_t, mH, sH, x, y, gamma, out);
}

// Round 10
// 64.324 us; speedup vs baseline: 1.0591x; 1.0591x over previous
//
#include <hip/hip_runtime.h>
#include <hip/hip_bf16.h>

// Problem constants: B=8, C=64, C8=8, H=128, W=128
#define BDIM 8
#define CDIM 64
#define C8DIM 8
#define HDIM 128
#define WDIM 128
#define HW (HDIM * WDIM)   // 16384

typedef short bf16x8 __attribute__((ext_vector_type(8)));
typedef float f32x4 __attribute__((ext_vector_type(4)));

// ---------------- bf16 helpers ----------------
__device__ inline unsigned pk_bf16(float a, float b) {
    unsigned ua = (unsigned)__bfloat16_as_ushort(__float2bfloat16(a));
    unsigned ub = (unsigned)__bfloat16_as_ushort(__float2bfloat16(b));
    return ua | (ub << 16);
}
__device__ inline void cvt2(unsigned u, float& lo, float& hi) {
    lo = __uint_as_float(u << 16);
    hi = __uint_as_float(u & 0xffff0000u);
}

// ---------------------------------------------------------------------------
// Kernel 1: fused QKV projection as MFMA GEMM.
//   D[o][p] = sum_c Wall[o][c] * X[c][p],  o in [0,80), c in [0,128)
// 1024 blocks x 512 threads (8 waves): block = (b, 128-position tile); each
// wave owns ONE 16-position n-tile (acc[5], 20 MFMA), so 4 blocks/CU x 8
// waves = 32 waves/CU (100% occupancy cap) for latency hiding.
// Weights: LDS bf16 [o][c] XOR-swizzled, staged once (10 iters/thread).
// X/Y: direct per-lane global loads (64B segments per 16-lane group).
// C/D layout: col = lane&15 (p), row = (lane>>4)*4 + reg (o) [HW-verified].
// ---------------------------------------------------------------------------
__global__ __launch_bounds__(512) void qkv_kernel(
    const float* __restrict__ x, const float* __restrict__ y,
    const float* __restrict__ Wq, const float* __restrict__ bq,
    const float* __restrict__ Wk, const float* __restrict__ bk,
    const float* __restrict__ Wv, const float* __restrict__ bv,
    uint4* __restrict__ q_pm, uint4* __restrict__ k_pm, uint4* __restrict__ v_pm)
{
    __shared__ ushort sW[80 * 128];   // [o][c] bf16, XOR-swizzled
    __shared__ float  sb[80];

    const int t = threadIdx.x;

    // ---- stage weights: 80x64 uint (=2 bf16) elements, 10 iters/thread ----
    for (int i = t; i < 80 * 64; i += 512) {
        int o  = i >> 6;
        int cp = i & 63;
        int c  = cp * 2;
        float w0, w1;
        if (o < 8) {
            if (c < 64) { w0 = Wq[o * 64 + c]; w1 = Wq[o * 64 + c + 1]; }
            else        { w0 = 0.f; w1 = 0.f; }
        } else if (o < 16) {
            if (c >= 64) { w0 = Wk[(o - 8) * 64 + c - 64]; w1 = Wk[(o - 8) * 64 + c - 63]; }
            else         { w0 = 0.f; w1 = 0.f; }
        } else {
            w0 = Wv[(o - 16) * 128 + c];
            w1 = Wv[(o - 16) * 128 + c + 1];
        }
        ((unsigned*)sW)[o * 64 + (cp ^ ((o & 7) << 2))] = pk_bf16(w0, w1);
    }
    if (t < 80) {
        sb[t] = (t < 8) ? bq[t] : (t < 16) ? bk[t - 8] : bv[t - 16];
    }
    __syncthreads();

    const int blk = blockIdx.x;
    const int b   = blk & 7;
    const int p0  = (blk >> 3) << 7;    // position tile base

    const int wv = t >> 6, ln = t & 63, lg = ln >> 4, li = ln & 15;
    const int pcol = p0 + wv * 16 + li;    // this lane's position

    const float* xb = x + (size_t)b * CDIM * HW;
    const float* yb = y + (size_t)b * CDIM * HW;

    f32x4 acc[5];
    #pragma unroll
    for (int mt = 0; mt < 5; mt++) acc[mt] = (f32x4){0.f, 0.f, 0.f, 0.f};

    #pragma unroll
    for (int pair = 0; pair < 2; pair++) {
        const int chb = pair * 32 + lg * 8;          // x/y channel base
        const float* xp = xb + (size_t)chb * HW + pcol;
        const float* yp = yb + (size_t)chb * HW + pcol;
        float fx[8], fy[8];
        #pragma unroll
        for (int e = 0; e < 8; e++) {
            fx[e] = xp[(size_t)e * HW];
            fy[e] = yp[(size_t)e * HW];
        }
        uint4 ux, uy;
        ux.x = pk_bf16(fx[0], fx[1]); ux.y = pk_bf16(fx[2], fx[3]);
        ux.z = pk_bf16(fx[4], fx[5]); ux.w = pk_bf16(fx[6], fx[7]);
        uy.x = pk_bf16(fy[0], fy[1]); uy.y = pk_bf16(fy[2], fy[3]);
        uy.z = pk_bf16(fy[4], fy[5]); uy.w = pk_bf16(fy[6], fy[7]);
        bf16x8 bx = *(bf16x8*)&ux;
        bf16x8 by = *(bf16x8*)&uy;

        #pragma unroll
        for (int mt = 0; mt < 5; mt++) {
            const int row = mt * 16 + li;
            const int sw  = ((li & 7) << 3);
            bf16x8 ax = *(const bf16x8*)&sW[row * 128 + ((pair * 32 + lg * 8) ^ sw)];
            bf16x8 ay = *(const bf16x8*)&sW[row * 128 + (((2 + pair) * 32 + lg * 8) ^ sw)];
            acc[mt] = __builtin_amdgcn_mfma_f32_16x16x32_bf16(ax, bx, acc[mt], 0, 0, 0);
            acc[mt] = __builtin_amdgcn_mfma_f32_16x16x32_bf16(ay, by, acc[mt], 0, 0, 0);
        }
    }

    // ---- epilogue: +bias, pack 4 contiguous o, direct store (pos-major) ----
    const size_t gp = (size_t)b * HW + (size_t)pcol;
    #pragma unroll
    for (int mt = 0; mt < 5; mt++) {
        const int ob = mt * 16 + lg * 4;   // o base (multiple of 4)
        uint2 w;
        w.x = pk_bf16(acc[mt][0] + sb[ob + 0], acc[mt][1] + sb[ob + 1]);
        w.y = pk_bf16(acc[mt][2] + sb[ob + 2], acc[mt][3] + sb[ob + 3]);
        ushort* dst;
        if (ob < 8)       dst = (ushort*)q_pm + gp * 8 + ob;
        else if (ob < 16) dst = (ushort*)k_pm + gp * 8 + (ob - 8);
        else              dst = (ushort*)v_pm + gp * 64 + (ob - 16);
        *(uint2*)dst = w;
    }
}

// ---------------------------------------------------------------------------
// Kernel 2 (column branch): one block per (b, c).  MFMA tile-GEMMs:
//   QK^T (swapped): D[j][i] = sum_ch K[j][ch] * Q[ch][i]
//   per-row (i) softmax with diag mask, unnormalized
//   PV: D2[ch][i] = sum_j V[ch][j] * P[j][i]
// H_t[b][row=i][col=cc][ch] stored via P_lds-reuse transpose (full-line writes).
// ---------------------------------------------------------------------------
__global__ __launch_bounds__(256, 2) void colattn_kernel(
    const uint4* __restrict__ q_pm, const uint4* __restrict__ k_pm,
    const uint4* __restrict__ v_pm,
    ushort* __restrict__ H_t, float* __restrict__ mH_g, float* __restrict__ sH_g)
{
    __shared__ ushort Q_lds[128 * 8];     // [i][ch]
    __shared__ ushort K_lds[128 * 8];     // [j][ch]
    __shared__ ushort V_lds[64 * 136];    // [ch][j], pad 8
    __shared__ ushort P_lds[128 * 136];   // [i][j], pad 8; reused for H store

    const int blk = blockIdx.x;
    const int b  = blk & 7;
    const int cc = blk >> 3;
    const int t  = threadIdx.x;

    if (t < 128) {
        *(uint4*)&Q_lds[t * 8] = q_pm[(size_t)b * HW + (size_t)t * 128 + cc];
    } else {
        int j = t - 128;
        *(uint4*)&K_lds[j * 8] = k_pm[(size_t)b * HW + (size_t)j * 128 + cc];
    }
    {
        int j = t & 127, h = t >> 7;
        const uint4* vp = v_pm + ((size_t)b * HW + (size_t)j * 128 + cc) * 8 + 4 * h;
        #pragma unroll
        for (int qd = 0; qd < 4; qd++) {
            uint4 vu = vp[qd];
            int ch0 = 32 * h + 8 * qd;
            V_lds[(ch0 + 0) * 136 + j] = (ushort)(vu.x & 0xffff);
            V_lds[(ch0 + 1) * 136 + j] = (ushort)(vu.x >> 16);
            V_lds[(ch0 + 2) * 136 + j] = (ushort)(vu.y & 0xffff);
            V_lds[(ch0 + 3) * 136 + j] = (ushort)(vu.y >> 16);
            V_lds[(ch0 + 4) * 136 + j] = (ushort)(vu.z & 0xffff);
            V_lds[(ch0 + 5) * 136 + j] = (ushort)(vu.z >> 16);
            V_lds[(ch0 + 6) * 136 + j] = (ushort)(vu.w & 0xffff);
            V_lds[(ch0 + 7) * 136 + j] = (ushort)(vu.w >> 16);
        }
    }
    __syncthreads();

    const int wv = t >> 6, ln = t & 63, lg = ln >> 4, li = ln & 15;
    const bf16x8 zf = {0, 0, 0, 0, 0, 0, 0, 0};

    // ---- QK^T ----
    bf16x8 afr[8], bfr[2];
    #pragma unroll
    for (int jt = 0; jt < 8; jt++)
        afr[jt] = (lg == 0) ? *(const bf16x8*)&K_lds[(jt * 16 + li) * 8] : zf;
    #pragma unroll
    for (int it2 = 0; it2 < 2; it2++)
        bfr[it2] = (lg == 0) ? *(const bf16x8*)&Q_lds[((2 * wv + it2) * 16 + li) * 8] : zf;

    f32x4 dfr[2][8];
    #pragma unroll
    for (int a = 0; a < 2; a++)
        #pragma unroll
        for (int jt = 0; jt < 8; jt++) dfr[a][jt] = (f32x4){0.f, 0.f, 0.f, 0.f};

    #pragma unroll
    for (int it2 = 0; it2 < 2; it2++)
        #pragma unroll
        for (int jt = 0; jt < 8; jt++)
            dfr[it2][jt] = __builtin_amdgcn_mfma_f32_16x16x32_bf16(
                afr[jt], bfr[it2], dfr[it2][jt], 0, 0, 0);

    // ---- softmax (unnormalized, diag masked) ----
    #pragma unroll
    for (int it2 = 0; it2 < 2; it2++) {
        const int i = (2 * wv + it2) * 16 + li;
        float m = -1e30f;
        #pragma unroll
        for (int jt = 0; jt < 8; jt++)
            #pragma unroll
            for (int rr = 0; rr < 4; rr++) {
                int j = jt * 16 + lg * 4 + rr;
                float e = dfr[it2][jt][rr];
                if (j == i) e = -1e30f;
                dfr[it2][jt][rr] = e;
                m = fmaxf(m, e);
            }
        m = fmaxf(m, __shfl_xor(m, 16));
        m = fmaxf(m, __shfl_xor(m, 32));
        float s = 0.f;
        #pragma unroll
        for (int jt = 0; jt < 8; jt++)
            #pragma unroll
            for (int rr = 0; rr < 4; rr++) {
                float p = __expf(dfr[it2][jt][rr] - m);
                dfr[it2][jt][rr] = p;
                s += p;
            }
        s += __shfl_xor(s, 16);
        s += __shfl_xor(s, 32);
        #pragma unroll
        for (int jt = 0; jt < 8; jt++) {
            uint2 w;
            w.x = pk_bf16(dfr[it2][jt][0], dfr[it2][jt][1]);
            w.y = pk_bf16(dfr[it2][jt][2], dfr[it2][jt][3]);
            *(uint2*)&P_lds[(size_t)i * 136 + jt * 16 + lg * 4] = w;
        }
        if (lg == 0) {
            mH_g[((size_t)b * 128 + cc) * 128 + i] = m;
            sH_g[((size_t)b * 128 + cc) * 128 + i] = s;
        }
    }
    __syncthreads();

    // ---- PV ----
    f32x4 ofr[8];
    #pragma unroll
    for (int itl = 0; itl < 8; itl++) ofr[itl] = (f32x4){0.f, 0.f, 0.f, 0.f};

    #pragma unroll
    for (int ks = 0; ks < 4; ks++) {
        const int jb = ks * 32 + lg * 8;
        bf16x8 av = *(const bf16x8*)&V_lds[(wv * 16 + li) * 136 + jb];
        #pragma unroll
        for (int itl = 0; itl < 8; itl++) {
            bf16x8 bp = *(const bf16x8*)&P_lds[(itl * 16 + li) * 136 + jb];
            ofr[itl] = __builtin_amdgcn_mfma_f32_16x16x32_bf16(av, bp, ofr[itl], 0, 0, 0);
        }
    }
    __syncthreads();   // P_lds dead; reuse as H transpose buffer [128][72]

    #pragma unroll
    for (int itl = 0; itl < 8; itl++) {
        const int i = itl * 16 + li;
        uint2 w;
        w.x = pk_bf16(ofr[itl][0], ofr[itl][1]);
        w.y = pk_bf16(ofr[itl][2], ofr[itl][3]);
        *(uint2*)&P_lds[i * 72 + wv * 16 + lg * 4] = w;
    }
    __syncthreads();

    #pragma unroll
    for (int i2 = 0; i2 < 4; i2++) {
        const int f = t + i2 * 256;          // 128 i x 8 chunks
        const int i = f >> 3, cb = (f & 7) * 8;
        *(uint4*)&H_t[(((size_t)b * 128 + i) * 128 + cc) * 64 + cb] =
            *(const uint4*)&P_lds[i * 72 + cb];
    }
}

// ---------------------------------------------------------------------------
// Kernel 3 (row branch + merge): one block per (b, r).  Same GEMM structure
// (no diag mask); epilogue merges with the column branch (mH/sH/H_t) and adds
// the residual:  out = (H*wH + W*wW) * gamma/(sH*wH + sW*wW) + x + y.
// x,y read as fp32 at the same index as the out write (coalesced, L3-hot).
// ---------------------------------------------------------------------------
__global__ __launch_bounds__(256, 2) void rowattn_kernel(
    const uint4* __restrict__ q_pm, const uint4* __restrict__ k_pm,
    const uint4* __restrict__ v_pm,
    const ushort* __restrict__ H_t, const float* __restrict__ mH_g,
    const float* __restrict__ sH_g,
    const float* __restrict__ x, const float* __restrict__ y,
    const float* __restrict__ gptr, float* __restrict__ out)
{
    __shared__ ushort Q_lds[128 * 8];     // [i][ch]  (i = column index)
    __shared__ ushort K_lds[128 * 8];     // [j][ch]
    __shared__ ushort V_lds[64 * 136];    // [ch][j]
    __shared__ ushort P_lds[128 * 136];   // [i][j]
    __shared__ float mW_s[128], sW_s[128];

    const int blk = blockIdx.x;
    const int b = blk & 7;
    const int r = blk >> 3;
    const int t = threadIdx.x;

    if (t < 128) {
        *(uint4*)&Q_lds[t * 8] = q_pm[(size_t)b * HW + (size_t)r * 128 + t];
    } else {
        int j = t - 128;
        *(uint4*)&K_lds[j * 8] = k_pm[(size_t)b * HW + (size_t)r * 128 + j];
    }
    {
        int j = t & 127, h = t >> 7;
        const uint4* vp = v_pm + ((size_t)b * HW + (size_t)r * 128 + j) * 8 + 4 * h;
        #pragma unroll
        for (int qd = 0; qd < 4; qd++) {
            uint4 vu = vp[qd];
            int ch0 = 32 * h + 8 * qd;
            V_lds[(ch0 + 0) * 136 + j] = (ushort)(vu.x & 0xffff);
            V_lds[(ch0 + 1) * 136 + j] = (ushort)(vu.x >> 16);
            V_lds[(ch0 + 2) * 136 + j] = (ushort)(vu.y & 0xffff);
            V_lds[(ch0 + 3) * 136 + j] = (ushort)(vu.y >> 16);
            V_lds[(ch0 + 4) * 136 + j] = (ushort)(vu.z & 0xffff);
            V_lds[(ch0 + 5) * 136 + j] = (ushort)(vu.z >> 16);
            V_lds[(ch0 + 6) * 136 + j] = (ushort)(vu.w & 0xffff);
            V_lds[(ch0 + 7) * 136 + j] = (ushort)(vu.w >> 16);
        }
    }
    __syncthreads();

    const int wv = t >> 6, ln = t & 63, lg = ln >> 4, li = ln & 15;
    const bf16x8 zf = {0, 0, 0, 0, 0, 0, 0, 0};

    bf16x8 afr[8], bfr[2];
    #pragma unroll
    for (int jt = 0; jt < 8; jt++)
        afr[jt] = (lg == 0) ? *(const bf16x8*)&K_lds[(jt * 16 + li) * 8] : zf;
    #pragma unroll
    for (int it2 = 0; it2 < 2; it2++)
        bfr[it2] = (lg == 0) ? *(const bf16x8*)&Q_lds[((2 * wv + it2) * 16 + li) * 8] : zf;

    f32x4 dfr[2][8];
    #pragma unroll
    for (int a = 0; a < 2; a++)
        #pragma unroll
        for (int jt = 0; jt < 8; jt++) dfr[a][jt] = (f32x4){0.f, 0.f, 0.f, 0.f};

    #pragma unroll
    for (int it2 = 0; it2 < 2; it2++)
        #pragma unroll
        for (int jt = 0; jt < 8; jt++)
            dfr[it2][jt] = __builtin_amdgcn_mfma_f32_16x16x32_bf16(
                afr[jt], bfr[it2], dfr[it2][jt], 0, 0, 0);

    #pragma unroll
    for (int it2 = 0; it2 < 2; it2++) {
        const int i = (2 * wv + it2) * 16 + li;
        float m = -1e30f;
        #pragma unroll
        for (int jt = 0; jt < 8; jt++)
            #pragma unroll
            for (int rr = 0; rr < 4; rr++)
                m = fmaxf(m, dfr[it2][jt][rr]);
        m = fmaxf(m, __shfl_xor(m, 16));
        m = fmaxf(m, __shfl_xor(m, 32));
        float s = 0.f;
        #pragma unroll
        for (int jt = 0; jt < 8; jt++)
            #pragma unroll
            for (int rr = 0; rr < 4; rr++) {
                float p = __expf(dfr[it2][jt][rr] - m);
                dfr[it2][jt][rr] = p;
                s += p;
            }
        s += __shfl_xor(s, 16);
        s += __shfl_xor(s, 32);
        #pragma unroll
        for (int jt = 0; jt < 8; jt++) {
            uint2 w;
            w.x = pk_bf16(dfr[it2][jt][0], dfr[it2][jt][1]);
            w.y = pk_bf16(dfr[it2][jt][2], dfr[it2][jt][3]);
            *(uint2*)&P_lds[(size_t)i * 136 + jt * 16 + lg * 4] = w;
        }
        if (lg == 0) {
            mW_s[i] = m;
            sW_s[i] = s;
        }
    }
    __syncthreads();

    f32x4 ofr[8];
    #pragma unroll
    for (int itl = 0; itl < 8; itl++) ofr[itl] = (f32x4){0.f, 0.f, 0.f, 0.f};

    #pragma unroll
    for (int ks = 0; ks < 4; ks++) {
        const int jb = ks * 32 + lg * 8;
        bf16x8 av = *(const bf16x8*)&V_lds[(wv * 16 + li) * 136 + jb];
        #pragma unroll
        for (int itl = 0; itl < 8; itl++) {
            bf16x8 bp = *(const bf16x8*)&P_lds[(itl * 16 + li) * 136 + jb];
            ofr[itl] = __builtin_amdgcn_mfma_f32_16x16x32_bf16(av, bp, ofr[itl], 0, 0, 0);
        }
    }

    const float gamma = gptr[0];
    #pragma unroll
    for (int itl = 0; itl < 8; itl++) {
        const int i = itl * 16 + li;     // column index of this position
        float mWv = mW_s[i], sWv = sW_s[i];
        float mHv = mH_g[((size_t)b * 128 + i) * 128 + r];
        float sHv = sH_g[((size_t)b * 128 + i) * 128 + r];
        float m  = fmaxf(mHv, mWv);
        float wH = __expf(mHv - m);
        float wW = __expf(mWv - m);
        float invg = gamma / (sHv * wH + sWv * wW);

        // coalesced-footprint H read: [b][r][i][ch], 8B per lane per itl
        uint2 hw = *(const uint2*)&H_t[(((size_t)b * 128 + r) * 128 + i) * 64 + wv * 16 + lg * 4];
        float h[4];
        cvt2(hw.x, h[0], h[1]);
        cvt2(hw.y, h[2], h[3]);

        #pragma unroll
        for (int rr = 0; rr < 4; rr++) {
            const int ch = wv * 16 + lg * 4 + rr;
            size_t o = (((size_t)b * 64 + ch) * 128 + r) * 128 + i;
            out[o] = (h[rr] * wH + ofr[itl][rr] * wW) * invg + x[o] + y[o];
        }
    }
}

// ---------------------------------------------------------------------------
extern "C" void kernel_launch(void* const* d_in, const int* in_sizes, int n_in,
                              void* d_out, int out_size, void* d_ws, size_t ws_size,
                              hipStream_t stream)
{
    const float* x     = (const float*)d_in[0];
    const float* y     = (const float*)d_in[1];
    const float* Wq    = (const float*)d_in[2];
    const float* bq    = (const float*)d_in[3];
    const float* Wk    = (const float*)d_in[4];
    const float* bk    = (const float*)d_in[5];
    const float* Wv    = (const float*)d_in[6];
    const float* bv    = (const float*)d_in[7];
    const float* gamma = (const float*)d_in[8];
    float* out = (float*)d_out;

    // Workspace: q 2MB | k 2MB | v 16MB | H_t 16MB | mH .5MB | sH .5MB
    uint4*  q_pm = (uint4*)d_ws;                        // 131072 uint4
    uint4*  k_pm = q_pm + (size_t)BDIM * HW;            // 131072 uint4
    uint4*  v_pm = k_pm + (size_t)BDIM * HW;            // 1048576 uint4
    ushort* H_t  = (ushort*)(v_pm + (size_t)BDIM * HW * 8);      // 8388608 us
    float*  mH   = (float*)(H_t + (size_t)BDIM * HW * 64);
    float*  sH   = mH + (size_t)BDIM * HW;

    qkv_kernel<<<dim3(BDIM * HW / 128), dim3(512), 0, stream>>>(
        x, y, Wq, bq, Wk, bk, Wv, bv, q_pm, k_pm, v_pm);

    colattn_kernel<<<dim3(BDIM * WDIM), dim3(256), 0, stream>>>(
        q_pm, k_pm, v_pm, H_t, mH, sH);

    rowattn_kernel<<<dim3(BDIM * HDIM), dim3(256), 0, stream>>>(
        q_pm, k_pm, v_pm, H_t, mH, sH, x, y, gamma, out);
}

// Round 11
// 63.162 us; speedup vs baseline: 1.0786x; 1.0184x over previous
//
#include <hip/hip_runtime.h>
#include <hip/hip_bf16.h>

// Problem constants: B=8, C=64, C8=8, H=128, W=128
#define BDIM 8
#define CDIM 64
#define C8DIM 8
#define HDIM 128
#define WDIM 128
#define HW (HDIM * WDIM)   // 16384

typedef short bf16x8 __attribute__((ext_vector_type(8)));
typedef float f32x4 __attribute__((ext_vector_type(4)));

// ---------------- bf16 helpers ----------------
__device__ inline unsigned pk_bf16(float a, float b) {
    unsigned ua = (unsigned)__bfloat16_as_ushort(__float2bfloat16(a));
    unsigned ub = (unsigned)__bfloat16_as_ushort(__float2bfloat16(b));
    return ua | (ub << 16);
}
__device__ inline void cvt2(unsigned u, float& lo, float& hi) {
    lo = __uint_as_float(u << 16);
    hi = __uint_as_float(u & 0xffff0000u);
}

// ---------------------------------------------------------------------------
// Kernel 1: fused QKV projection as MFMA GEMM (unchanged from round 10).
// 1024 blocks x 512 threads (8 waves); wave owns one 16-position n-tile.
// ---------------------------------------------------------------------------
__global__ __launch_bounds__(512) void qkv_kernel(
    const float* __restrict__ x, const float* __restrict__ y,
    const float* __restrict__ Wq, const float* __restrict__ bq,
    const float* __restrict__ Wk, const float* __restrict__ bk,
    const float* __restrict__ Wv, const float* __restrict__ bv,
    uint4* __restrict__ q_pm, uint4* __restrict__ k_pm, uint4* __restrict__ v_pm)
{
    __shared__ ushort sW[80 * 128];   // [o][c] bf16, XOR-swizzled
    __shared__ float  sb[80];

    const int t = threadIdx.x;

    for (int i = t; i < 80 * 64; i += 512) {
        int o  = i >> 6;
        int cp = i & 63;
        int c  = cp * 2;
        float w0, w1;
        if (o < 8) {
            if (c < 64) { w0 = Wq[o * 64 + c]; w1 = Wq[o * 64 + c + 1]; }
            else        { w0 = 0.f; w1 = 0.f; }
        } else if (o < 16) {
            if (c >= 64) { w0 = Wk[(o - 8) * 64 + c - 64]; w1 = Wk[(o - 8) * 64 + c - 63]; }
            else         { w0 = 0.f; w1 = 0.f; }
        } else {
            w0 = Wv[(o - 16) * 128 + c];
            w1 = Wv[(o - 16) * 128 + c + 1];
        }
        ((unsigned*)sW)[o * 64 + (cp ^ ((o & 7) << 2))] = pk_bf16(w0, w1);
    }
    if (t < 80) {
        sb[t] = (t < 8) ? bq[t] : (t < 16) ? bk[t - 8] : bv[t - 16];
    }
    __syncthreads();

    const int blk = blockIdx.x;
    const int b   = blk & 7;
    const int p0  = (blk >> 3) << 7;

    const int wv = t >> 6, ln = t & 63, lg = ln >> 4, li = ln & 15;
    const int pcol = p0 + wv * 16 + li;

    const float* xb = x + (size_t)b * CDIM * HW;
    const float* yb = y + (size_t)b * CDIM * HW;

    f32x4 acc[5];
    #pragma unroll
    for (int mt = 0; mt < 5; mt++) acc[mt] = (f32x4){0.f, 0.f, 0.f, 0.f};

    #pragma unroll
    for (int pair = 0; pair < 2; pair++) {
        const int chb = pair * 32 + lg * 8;
        const float* xp = xb + (size_t)chb * HW + pcol;
        const float* yp = yb + (size_t)chb * HW + pcol;
        float fx[8], fy[8];
        #pragma unroll
        for (int e = 0; e < 8; e++) {
            fx[e] = xp[(size_t)e * HW];
            fy[e] = yp[(size_t)e * HW];
        }
        uint4 ux, uy;
        ux.x = pk_bf16(fx[0], fx[1]); ux.y = pk_bf16(fx[2], fx[3]);
        ux.z = pk_bf16(fx[4], fx[5]); ux.w = pk_bf16(fx[6], fx[7]);
        uy.x = pk_bf16(fy[0], fy[1]); uy.y = pk_bf16(fy[2], fy[3]);
        uy.z = pk_bf16(fy[4], fy[5]); uy.w = pk_bf16(fy[6], fy[7]);
        bf16x8 bx = *(bf16x8*)&ux;
        bf16x8 by = *(bf16x8*)&uy;

        #pragma unroll
        for (int mt = 0; mt < 5; mt++) {
            const int row = mt * 16 + li;
            const int sw  = ((li & 7) << 3);
            bf16x8 ax = *(const bf16x8*)&sW[row * 128 + ((pair * 32 + lg * 8) ^ sw)];
            bf16x8 ay = *(const bf16x8*)&sW[row * 128 + (((2 + pair) * 32 + lg * 8) ^ sw)];
            acc[mt] = __builtin_amdgcn_mfma_f32_16x16x32_bf16(ax, bx, acc[mt], 0, 0, 0);
            acc[mt] = __builtin_amdgcn_mfma_f32_16x16x32_bf16(ay, by, acc[mt], 0, 0, 0);
        }
    }

    const size_t gp = (size_t)b * HW + (size_t)pcol;
    #pragma unroll
    for (int mt = 0; mt < 5; mt++) {
        const int ob = mt * 16 + lg * 4;
        uint2 w;
        w.x = pk_bf16(acc[mt][0] + sb[ob + 0], acc[mt][1] + sb[ob + 1]);
        w.y = pk_bf16(acc[mt][2] + sb[ob + 2], acc[mt][3] + sb[ob + 3]);
        ushort* dst;
        if (ob < 8)       dst = (ushort*)q_pm + gp * 8 + ob;
        else if (ob < 16) dst = (ushort*)k_pm + gp * 8 + (ob - 8);
        else              dst = (ushort*)v_pm + gp * 64 + (ob - 16);
        *(uint2*)dst = w;
    }
}

// ---------------------------------------------------------------------------
// Kernel 2 (column branch): one block per (b, c).  V/P in LDS are XOR-swizzled
// (ushort col ^= ((row&7)<<3)) instead of padded -> 52 KB LDS -> 3 blocks/CU.
// ---------------------------------------------------------------------------
__global__ __launch_bounds__(256, 3) void colattn_kernel(
    const uint4* __restrict__ q_pm, const uint4* __restrict__ k_pm,
    const uint4* __restrict__ v_pm,
    ushort* __restrict__ H_t, float* __restrict__ mH_g, float* __restrict__ sH_g)
{
    __shared__ ushort Q_lds[128 * 8];     // [i][ch]
    __shared__ ushort K_lds[128 * 8];     // [j][ch]
    __shared__ ushort V_lds[64 * 128];    // [ch][j], XOR-swizzled
    __shared__ ushort P_lds[128 * 128];   // [i][j], XOR-swizzled; reused for H

    const int blk = blockIdx.x;
    const int b  = blk & 7;
    const int cc = blk >> 3;
    const int t  = threadIdx.x;

    if (t < 128) {
        *(uint4*)&Q_lds[t * 8] = q_pm[(size_t)b * HW + (size_t)t * 128 + cc];
    } else {
        int j = t - 128;
        *(uint4*)&K_lds[j * 8] = k_pm[(size_t)b * HW + (size_t)j * 128 + cc];
    }
    {
        int j = t & 127, h = t >> 7;
        const uint4* vp = v_pm + ((size_t)b * HW + (size_t)j * 128 + cc) * 8 + 4 * h;
        #pragma unroll
        for (int qd = 0; qd < 4; qd++) {
            uint4 vu = vp[qd];
            int ch0 = 32 * h + 8 * qd;     // multiple of 8
            V_lds[(ch0 + 0) * 128 + (j ^ (0 << 3))] = (ushort)(vu.x & 0xffff);
            V_lds[(ch0 + 1) * 128 + (j ^ (1 << 3))] = (ushort)(vu.x >> 16);
            V_lds[(ch0 + 2) * 128 + (j ^ (2 << 3))] = (ushort)(vu.y & 0xffff);
            V_lds[(ch0 + 3) * 128 + (j ^ (3 << 3))] = (ushort)(vu.y >> 16);
            V_lds[(ch0 + 4) * 128 + (j ^ (4 << 3))] = (ushort)(vu.z & 0xffff);
            V_lds[(ch0 + 5) * 128 + (j ^ (5 << 3))] = (ushort)(vu.z >> 16);
            V_lds[(ch0 + 6) * 128 + (j ^ (6 << 3))] = (ushort)(vu.w & 0xffff);
            V_lds[(ch0 + 7) * 128 + (j ^ (7 << 3))] = (ushort)(vu.w >> 16);
        }
    }
    __syncthreads();

    const int wv = t >> 6, ln = t & 63, lg = ln >> 4, li = ln & 15;
    const bf16x8 zf = {0, 0, 0, 0, 0, 0, 0, 0};

    // ---- QK^T ----
    bf16x8 afr[8], bfr[2];
    #pragma unroll
    for (int jt = 0; jt < 8; jt++)
        afr[jt] = (lg == 0) ? *(const bf16x8*)&K_lds[(jt * 16 + li) * 8] : zf;
    #pragma unroll
    for (int it2 = 0; it2 < 2; it2++)
        bfr[it2] = (lg == 0) ? *(const bf16x8*)&Q_lds[((2 * wv + it2) * 16 + li) * 8] : zf;

    f32x4 dfr[2][8];
    #pragma unroll
    for (int a = 0; a < 2; a++)
        #pragma unroll
        for (int jt = 0; jt < 8; jt++) dfr[a][jt] = (f32x4){0.f, 0.f, 0.f, 0.f};

    #pragma unroll
    for (int it2 = 0; it2 < 2; it2++)
        #pragma unroll
        for (int jt = 0; jt < 8; jt++)
            dfr[it2][jt] = __builtin_amdgcn_mfma_f32_16x16x32_bf16(
                afr[jt], bfr[it2], dfr[it2][jt], 0, 0, 0);

    // ---- softmax (unnormalized, diag masked) ----
    #pragma unroll
    for (int it2 = 0; it2 < 2; it2++) {
        const int i = (2 * wv + it2) * 16 + li;
        float m = -1e30f;
        #pragma unroll
        for (int jt = 0; jt < 8; jt++)
            #pragma unroll
            for (int rr = 0; rr < 4; rr++) {
                int j = jt * 16 + lg * 4 + rr;
                float e = dfr[it2][jt][rr];
                if (j == i) e = -1e30f;
                dfr[it2][jt][rr] = e;
                m = fmaxf(m, e);
            }
        m = fmaxf(m, __shfl_xor(m, 16));
        m = fmaxf(m, __shfl_xor(m, 32));
        float s = 0.f;
        #pragma unroll
        for (int jt = 0; jt < 8; jt++)
            #pragma unroll
            for (int rr = 0; rr < 4; rr++) {
                float p = __expf(dfr[it2][jt][rr] - m);
                dfr[it2][jt][rr] = p;
                s += p;
            }
        s += __shfl_xor(s, 16);
        s += __shfl_xor(s, 32);
        const int swz = (i & 7) << 3;
        #pragma unroll
        for (int jt = 0; jt < 8; jt++) {
            uint2 w;
            w.x = pk_bf16(dfr[it2][jt][0], dfr[it2][jt][1]);
            w.y = pk_bf16(dfr[it2][jt][2], dfr[it2][jt][3]);
            *(uint2*)&P_lds[i * 128 + ((jt * 16 + lg * 4) ^ swz)] = w;
        }
        if (lg == 0) {
            mH_g[((size_t)b * 128 + cc) * 128 + i] = m;
            sH_g[((size_t)b * 128 + cc) * 128 + i] = s;
        }
    }
    __syncthreads();

    // ---- PV ----
    f32x4 ofr[8];
    #pragma unroll
    for (int itl = 0; itl < 8; itl++) ofr[itl] = (f32x4){0.f, 0.f, 0.f, 0.f};

    const int vswz = (li & 7) << 3;
    #pragma unroll
    for (int ks = 0; ks < 4; ks++) {
        const int jb = ks * 32 + lg * 8;
        bf16x8 av = *(const bf16x8*)&V_lds[(wv * 16 + li) * 128 + (jb ^ vswz)];
        #pragma unroll
        for (int itl = 0; itl < 8; itl++) {
            bf16x8 bp = *(const bf16x8*)&P_lds[(itl * 16 + li) * 128 + (jb ^ vswz)];
            ofr[itl] = __builtin_amdgcn_mfma_f32_16x16x32_bf16(av, bp, ofr[itl], 0, 0, 0);
        }
    }
    __syncthreads();   // P_lds dead; reuse as H transpose buffer [128][72]

    #pragma unroll
    for (int itl = 0; itl < 8; itl++) {
        const int i = itl * 16 + li;
        uint2 w;
        w.x = pk_bf16(ofr[itl][0], ofr[itl][1]);
        w.y = pk_bf16(ofr[itl][2], ofr[itl][3]);
        *(uint2*)&P_lds[i * 72 + wv * 16 + lg * 4] = w;
    }
    __syncthreads();

    #pragma unroll
    for (int i2 = 0; i2 < 4; i2++) {
        const int f = t + i2 * 256;          // 128 i x 8 chunks
        const int i = f >> 3, cb = (f & 7) * 8;
        *(uint4*)&H_t[(((size_t)b * 128 + i) * 128 + cc) * 64 + cb] =
            *(const uint4*)&P_lds[i * 72 + cb];
    }
}

// ---------------------------------------------------------------------------
// Kernel 3 (row branch + merge): one block per (b, r).  Same swizzled-LDS
// structure (53 KB -> 3 blocks/CU).  Epilogue merges col branch + residual.
// ---------------------------------------------------------------------------
__global__ __launch_bounds__(256, 3) void rowattn_kernel(
    const uint4* __restrict__ q_pm, const uint4* __restrict__ k_pm,
    const uint4* __restrict__ v_pm,
    const ushort* __restrict__ H_t, const float* __restrict__ mH_g,
    const float* __restrict__ sH_g,
    const float* __restrict__ x, const float* __restrict__ y,
    const float* __restrict__ gptr, float* __restrict__ out)
{
    __shared__ ushort Q_lds[128 * 8];     // [i][ch]  (i = column index)
    __shared__ ushort K_lds[128 * 8];     // [j][ch]
    __shared__ ushort V_lds[64 * 128];    // [ch][j], XOR-swizzled
    __shared__ ushort P_lds[128 * 128];   // [i][j], XOR-swizzled
    __shared__ float mW_s[128], sW_s[128];

    const int blk = blockIdx.x;
    const int b = blk & 7;
    const int r = blk >> 3;
    const int t = threadIdx.x;

    if (t < 128) {
        *(uint4*)&Q_lds[t * 8] = q_pm[(size_t)b * HW + (size_t)r * 128 + t];
    } else {
        int j = t - 128;
        *(uint4*)&K_lds[j * 8] = k_pm[(size_t)b * HW + (size_t)r * 128 + j];
    }
    {
        int j = t & 127, h = t >> 7;
        const uint4* vp = v_pm + ((size_t)b * HW + (size_t)r * 128 + j) * 8 + 4 * h;
        #pragma unroll
        for (int qd = 0; qd < 4; qd++) {
            uint4 vu = vp[qd];
            int ch0 = 32 * h + 8 * qd;
            V_lds[(ch0 + 0) * 128 + (j ^ (0 << 3))] = (ushort)(vu.x & 0xffff);
            V_lds[(ch0 + 1) * 128 + (j ^ (1 << 3))] = (ushort)(vu.x >> 16);
            V_lds[(ch0 + 2) * 128 + (j ^ (2 << 3))] = (ushort)(vu.y & 0xffff);
            V_lds[(ch0 + 3) * 128 + (j ^ (3 << 3))] = (ushort)(vu.y >> 16);
            V_lds[(ch0 + 4) * 128 + (j ^ (4 << 3))] = (ushort)(vu.z & 0xffff);
            V_lds[(ch0 + 5) * 128 + (j ^ (5 << 3))] = (ushort)(vu.z >> 16);
            V_lds[(ch0 + 6) * 128 + (j ^ (6 << 3))] = (ushort)(vu.w & 0xffff);
            V_lds[(ch0 + 7) * 128 + (j ^ (7 << 3))] = (ushort)(vu.w >> 16);
        }
    }
    __syncthreads();

    const int wv = t >> 6, ln = t & 63, lg = ln >> 4, li = ln & 15;
    const bf16x8 zf = {0, 0, 0, 0, 0, 0, 0, 0};

    bf16x8 afr[8], bfr[2];
    #pragma unroll
    for (int jt = 0; jt < 8; jt++)
        afr[jt] = (lg == 0) ? *(const bf16x8*)&K_lds[(jt * 16 + li) * 8] : zf;
    #pragma unroll
    for (int it2 = 0; it2 < 2; it2++)
        bfr[it2] = (lg == 0) ? *(const bf16x8*)&Q_lds[((2 * wv + it2) * 16 + li) * 8] : zf;

    f32x4 dfr[2][8];
    #pragma unroll
    for (int a = 0; a < 2; a++)
        #pragma unroll
        for (int jt = 0; jt < 8; jt++) dfr[a][jt] = (f32x4){0.f, 0.f, 0.f, 0.f};

    #pragma unroll
    for (int it2 = 0; it2 < 2; it2++)
        #pragma unroll
        for (int jt = 0; jt < 8; jt++)
            dfr[it2][jt] = __builtin_amdgcn_mfma_f32_16x16x32_bf16(
                afr[jt], bfr[it2], dfr[it2][jt], 0, 0, 0);

    #pragma unroll
    for (int it2 = 0; it2 < 2; it2++) {
        const int i = (2 * wv + it2) * 16 + li;
        float m = -1e30f;
        #pragma unroll
        for (int jt = 0; jt < 8; jt++)
            #pragma unroll
            for (int rr = 0; rr < 4; rr++)
                m = fmaxf(m, dfr[it2][jt][rr]);
        m = fmaxf(m, __shfl_xor(m, 16));
        m = fmaxf(m, __shfl_xor(m, 32));
        float s = 0.f;
        #pragma unroll
        for (int jt = 0; jt < 8; jt++)
            #pragma unroll
            for (int rr = 0; rr < 4; rr++) {
                float p = __expf(dfr[it2][jt][rr] - m);
                dfr[it2][jt][rr] = p;
                s += p;
            }
        s += __shfl_xor(s, 16);
        s += __shfl_xor(s, 32);
        const int swz = (i & 7) << 3;
        #pragma unroll
        for (int jt = 0; jt < 8; jt++) {
            uint2 w;
            w.x = pk_bf16(dfr[it2][jt][0], dfr[it2][jt][1]);
            w.y = pk_bf16(dfr[it2][jt][2], dfr[it2][jt][3]);
            *(uint2*)&P_lds[i * 128 + ((jt * 16 + lg * 4) ^ swz)] = w;
        }
        if (lg == 0) {
            mW_s[i] = m;
            sW_s[i] = s;
        }
    }
    __syncthreads();

    f32x4 ofr[8];
    #pragma unroll
    for (int itl = 0; itl < 8; itl++) ofr[itl] = (f32x4){0.f, 0.f, 0.f, 0.f};

    const int vswz = (li & 7) << 3;
    #pragma unroll
    for (int ks = 0; ks < 4; ks++) {
        const int jb = ks * 32 + lg * 8;
        bf16x8 av = *(const bf16x8*)&V_lds[(wv * 16 + li) * 128 + (jb ^ vswz)];
        #pragma unroll
        for (int itl = 0; itl < 8; itl++) {
            bf16x8 bp = *(const bf16x8*)&P_lds[(itl * 16 + li) * 128 + (jb ^ vswz)];
            ofr[itl] = __builtin_amdgcn_mfma_f32_16x16x32_bf16(av, bp, ofr[itl], 0, 0, 0);
        }
    }

    const float gamma = gptr[0];
    #pragma unroll
    for (int itl = 0; itl < 8; itl++) {
        const int i = itl * 16 + li;     // column index of this position
        float mWv = mW_s[i], sWv = sW_s[i];
        float mHv = mH_g[((size_t)b * 128 + i) * 128 + r];
        float sHv = sH_g[((size_t)b * 128 + i) * 128 + r];
        float m  = fmaxf(mHv, mWv);
        float wH = __expf(mHv - m);
        float wW = __expf(mWv - m);
        float invg = gamma / (sHv * wH + sWv * wW);

        uint2 hw = *(const uint2*)&H_t[(((size_t)b * 128 + r) * 128 + i) * 64 + wv * 16 + lg * 4];
        float h[4];
        cvt2(hw.x, h[0], h[1]);
        cvt2(hw.y, h[2], h[3]);

        #pragma unroll
        for (int rr = 0; rr < 4; rr++) {
            const int ch = wv * 16 + lg * 4 + rr;
            size_t o = (((size_t)b * 64 + ch) * 128 + r) * 128 + i;
            out[o] = (h[rr] * wH + ofr[itl][rr] * wW) * invg + x[o] + y[o];
        }
    }
}

// ---------------------------------------------------------------------------
extern "C" void kernel_launch(void* const* d_in, const int* in_sizes, int n_in,
                              void* d_out, int out_size, void* d_ws, size_t ws_size,
                              hipStream_t stream)
{
    const float* x     = (const float*)d_in[0];
    const float* y     = (const float*)d_in[1];
    const float* Wq    = (const float*)d_in[2];
    const float* bq    = (const float*)d_in[3];
    const float* Wk    = (const float*)d_in[4];
    const float* bk    = (const float*)d_in[5];
    const float* Wv    = (const float*)d_in[6];
    const float* bv    = (const float*)d_in[7];
    const float* gamma = (const float*)d_in[8];
    float* out = (float*)d_out;

    // Workspace: q 2MB | k 2MB | v 16MB | H_t 16MB | mH .5MB | sH .5MB
    uint4*  q_pm = (uint4*)d_ws;                        // 131072 uint4
    uint4*  k_pm = q_pm + (size_t)BDIM * HW;            // 131072 uint4
    uint4*  v_pm = k_pm + (size_t)BDIM * HW;            // 1048576 uint4
    ushort* H_t  = (ushort*)(v_pm + (size_t)BDIM * HW * 8);      // 8388608 us
    float*  mH   = (float*)(H_t + (size_t)BDIM * HW * 64);
    float*  sH   = mH + (size_t)BDIM * HW;

    qkv_kernel<<<dim3(BDIM * HW / 128), dim3(512), 0, stream>>>(
        x, y, Wq, bq, Wk, bk, Wv, bv, q_pm, k_pm, v_pm);

    colattn_kernel<<<dim3(BDIM * WDIM), dim3(256), 0, stream>>>(
        q_pm, k_pm, v_pm, H_t, mH, sH);

    rowattn_kernel<<<dim3(BDIM * HDIM), dim3(256), 0, stream>>>(
        q_pm, k_pm, v_pm, H_t, mH, sH, x, y, gamma, out);
}